// Round 1
// baseline (1466.486 us; speedup 1.0000x reference)
//
#include <hip/hip_runtime.h>
#include <math.h>

#define BATCH 16384
#define IND   362
#define KP    384      // per-feature K padded to 384 (12 x 32)
#define HID   256
#define STY   60
#define NOUT  49710
#define OUTP  49792    // padded o-stride for hbfT (389*128)
#define D2    724
#define D2P   768

typedef __bf16 bf16x8 __attribute__((ext_vector_type(8)));
typedef float  floatx4 __attribute__((ext_vector_type(4)));

__device__ inline floatx4 mfma16(bf16x8 a, bf16x8 b, floatx4 c) {
  return __builtin_amdgcn_mfma_f32_16x16x32_bf16(a, b, c, 0, 0, 0);
}

__device__ inline unsigned short f32_to_bf16(float x) {
  unsigned int u = __float_as_uint(x);
  unsigned int r = (u + 0x7FFFu + ((u >> 16) & 1u)) >> 16;
  return (unsigned short)r;
}

__device__ inline float sigm_fast(float x) { return 1.0f / (1.0f + __expf(-x)); }
__device__ inline float softplusf(float z) { return fmaxf(z, 0.0f) + log1pf(expf(-fabsf(z))); }

// ---------------- convert kernels ----------------

// features f32 (BATCH x 362) -> bf16 (BATCH x 384, zero-padded), 3 arrays
__global__ void k_conv_feat(const float* __restrict__ fi, const float* __restrict__ fj,
                            const float* __restrict__ fk, unsigned short* __restrict__ fbf) {
  int row = blockIdx.x;
  int f = blockIdx.y;
  const float* src = (f == 0) ? fi : (f == 1 ? fj : fk);
  unsigned short* dst = fbf + ((size_t)f * BATCH + row) * KP;
  for (int d = threadIdx.x; d < KP; d += blockDim.x) {
    float v = (d < IND) ? src[(size_t)row * IND + d] : 0.0f;
    dst[d] = f32_to_bf16(v);
  }
}

// W (362x256) -> wbfT [2][256][384] bf16 (transposed, k-padded)
__global__ void k_conv_w(const float* __restrict__ Wt, const float* __restrict__ Wb,
                         unsigned short* __restrict__ wbfT) {
  int h = blockIdx.x;
  int m = blockIdx.y;
  const float* W = m ? Wb : Wt;
  unsigned short* dst = wbfT + ((size_t)m * HID + h) * KP;
  for (int k = threadIdx.x; k < KP; k += blockDim.x) {
    float v = (k < IND) ? W[(size_t)k * HID + h] : 0.0f;
    dst[k] = f32_to_bf16(v);
  }
}

// P/N (724x60) relu -> pnbf [2][768][64] ([d][s]) and pnbfT [2][64][768] ([s][k], 384-split padding)
__global__ void k_conv_pn(const float* __restrict__ P, const float* __restrict__ N,
                          unsigned short* __restrict__ pnbf, unsigned short* __restrict__ pnbfT) {
  int d = blockIdx.x;   // 0..767
  int m = blockIdx.y;
  int s = threadIdx.x;  // 0..63
  const float* M = m ? N : P;
  float v = (d < D2 && s < STY) ? fmaxf(M[(size_t)d * STY + s], 0.0f) : 0.0f;
  unsigned short b = f32_to_bf16(v);
  pnbf[((size_t)m * D2P + d) * 64 + s] = b;
  // bijective pad mapping: d<362 -> k=d ; 362<=d<724 -> k=d+22 ; 724<=d<746 -> k=d-362 (pad) ; else k=d (pad)
  int k = (d < IND) ? d : (d < D2 ? d + 22 : (d < 746 ? d - IND : d));
  pnbfT[((size_t)m * 64 + s) * D2P + k] = b;
}

// H1/H2 (60x49710) relu -> hbfT [2][49792][64] bf16 (transposed [o][k])
__global__ void k_conv_h(const float* __restrict__ H1, const float* __restrict__ H2,
                         unsigned short* __restrict__ hbfT) {
  int o = blockIdx.x * 256 + threadIdx.x;
  int m = blockIdx.y;
  if (o >= OUTP) return;
  const float* H = m ? H2 : H1;
  unsigned short* dst = hbfT + ((size_t)m * OUTP + o) * 64;
  bool ov = (o < NOUT);
  #pragma unroll
  for (int g = 0; g < 8; g++) {
    unsigned int wv[4];
    #pragma unroll
    for (int e = 0; e < 4; e++) {
      int kk = g * 8 + e * 2;
      float lo = (ov && kk < STY)     ? fmaxf(H[(size_t)kk * NOUT + o], 0.0f) : 0.0f;
      float hi = (ov && kk + 1 < STY) ? fmaxf(H[(size_t)(kk + 1) * NOUT + o], 0.0f) : 0.0f;
      wv[e] = (unsigned)f32_to_bf16(lo) | ((unsigned)f32_to_bf16(hi) << 16);
    }
    uint4 v; v.x = wv[0]; v.y = wv[1]; v.z = wv[2]; v.w = wv[3];
    *(uint4*)(dst + g * 8) = v;
  }
}

// ---------------- K1: per-style scalar scores + column norms (fp32 exact) ----------------
__global__ __launch_bounds__(256) void k_style_scalar(
    const float* __restrict__ Pn, const float* __restrict__ Nn,
    const float* __restrict__ Wt, const float* __restrict__ btop,
    const float* __restrict__ Wb, const float* __restrict__ bbot,
    float* __restrict__ ss, float* __restrict__ cn) {
  int s  = blockIdx.x % STY;
  int mt = blockIdx.x / STY;
  const float* M = mt ? Nn : Pn;
  __shared__ float sel[D2];
  __shared__ float shr[4];
  int t = threadIdx.x;
  float cnp = 0.0f;
  for (int d = t; d < D2; d += 256) {
    float v = fmaxf(M[(size_t)d * STY + s], 0.0f);
    sel[d] = v;
    cnp += v * v;
  }
  __syncthreads();
  float at = btop[t], ab = bbot[t];
  for (int d = 0; d < IND; d++) at = fmaf(sel[d],        Wt[(size_t)d * HID + t], at);
  for (int d = 0; d < IND; d++) ab = fmaf(sel[IND + d],  Wb[(size_t)d * HID + t], ab);
  float prod = (1.0f / (1.0f + expf(-at))) * (1.0f / (1.0f + expf(-ab)));
  for (int off = 32; off > 0; off >>= 1) prod += __shfl_xor(prod, off);
  if ((t & 63) == 0) shr[t >> 6] = prod;
  __syncthreads();
  if (t == 0) ss[mt * 64 + s] = shr[0] + shr[1] + shr[2] + shr[3];
  __syncthreads();
  for (int off = 32; off > 0; off >>= 1) cnp += __shfl_xor(cnp, off);
  if ((t & 63) == 0) shr[t >> 6] = cnp;
  __syncthreads();
  if (t == 0) cn[mt * 64 + s] = shr[0] + shr[1] + shr[2] + shr[3];
}

// ---------------- K2: embedding GEMMs (MFMA) + ij/ik scores ----------------
// wave = 16 rows x 128 hidden ; grid (BATCH/64, 2)
__global__ __launch_bounds__(256) void k_emb(
    const unsigned short* __restrict__ fbf, const unsigned short* __restrict__ wbfT,
    const float* __restrict__ btop, const float* __restrict__ bbot,
    float* __restrict__ sIJ, float* __restrict__ sIK) {
  int w = threadIdx.x >> 6, lane = threadIdx.x & 63;
  int m = lane & 15, q = lane >> 4;
  int r0 = blockIdx.x * 64 + w * 16;
  int hb = blockIdx.y * 128;
  const unsigned short* fi = fbf + (size_t)(r0 + m) * KP + q * 8;
  const unsigned short* fj = fi + (size_t)BATCH * KP;
  const unsigned short* fk = fj + (size_t)BATCH * KP;
  floatx4 accI[8], accJ[8], accK[8];
  #pragma unroll
  for (int nt = 0; nt < 8; nt++) {
    accI[nt] = (floatx4){0.f, 0.f, 0.f, 0.f};
    accJ[nt] = (floatx4){0.f, 0.f, 0.f, 0.f};
    accK[nt] = (floatx4){0.f, 0.f, 0.f, 0.f};
  }
  for (int kc = 0; kc < 12; kc++) {
    bf16x8 ai = *(const bf16x8*)(fi + kc * 32);
    bf16x8 aj = *(const bf16x8*)(fj + kc * 32);
    bf16x8 ak = *(const bf16x8*)(fk + kc * 32);
    #pragma unroll
    for (int nt = 0; nt < 8; nt++) {
      int n = hb + nt * 16 + m;
      const unsigned short* wp = wbfT + (size_t)n * KP + kc * 32 + q * 8;
      bf16x8 bt8 = *(const bf16x8*)(wp);
      bf16x8 bb8 = *(const bf16x8*)(wp + (size_t)HID * KP);
      accI[nt] = mfma16(ai, bt8, accI[nt]);
      accJ[nt] = mfma16(aj, bb8, accJ[nt]);
      accK[nt] = mfma16(ak, bb8, accK[nt]);
    }
  }
  float sij[4] = {0.f, 0.f, 0.f, 0.f}, sik[4] = {0.f, 0.f, 0.f, 0.f};
  #pragma unroll
  for (int nt = 0; nt < 8; nt++) {
    int n = hb + nt * 16 + m;
    float vbt = btop[n], vbb = bbot[n];
    #pragma unroll
    for (int reg = 0; reg < 4; reg++) {
      float ti = sigm_fast(accI[nt][reg] + vbt);
      float tj = sigm_fast(accJ[nt][reg] + vbb);
      float tk = sigm_fast(accK[nt][reg] + vbb);
      sij[reg] += ti * tj;
      sik[reg] += ti * tk;
    }
  }
  #pragma unroll
  for (int reg = 0; reg < 4; reg++) {
    for (int off = 1; off < 16; off <<= 1) {
      sij[reg] += __shfl_xor(sij[reg], off);
      sik[reg] += __shfl_xor(sik[reg], off);
    }
  }
  if (m == 0) {
    #pragma unroll
    for (int reg = 0; reg < 4; reg++) {
      int row = r0 + q * 4 + reg;
      atomicAdd(&sIJ[row], sij[reg]);
      atomicAdd(&sIK[row], sik[reg]);
    }
  }
}

// ---------------- K3: style argmin + gather (MFMA) ----------------
// wave: mat = w&1, 16 rows; block covers 32 rows; grid 512
__global__ __launch_bounds__(256) void k_style_assign(
    const unsigned short* __restrict__ fbf, const unsigned short* __restrict__ pnbfT,
    const float* __restrict__ cn, const float* __restrict__ ss,
    float* __restrict__ stIJ, float* __restrict__ stIK) {
  int w = threadIdx.x >> 6, lane = threadIdx.x & 63;
  int m = lane & 15, q = lane >> 4;
  int mat = w & 1;
  int r0 = blockIdx.x * 32 + (w >> 1) * 16;
  const unsigned short* fA = fbf + (size_t)(r0 + m) * KP + q * 8;              // i
  const unsigned short* fB = fA + (size_t)(1 + mat) * BATCH * KP;              // j or k
  const unsigned short* Bp = pnbfT + (size_t)mat * 64 * D2P + q * 8;
  floatx4 acc[4];
  #pragma unroll
  for (int nt = 0; nt < 4; nt++) acc[nt] = (floatx4){0.f, 0.f, 0.f, 0.f};
  for (int kc = 0; kc < 24; kc++) {
    bf16x8 a = (kc < 12) ? *(const bf16x8*)(fA + kc * 32)
                         : *(const bf16x8*)(fB + (kc - 12) * 32);
    #pragma unroll
    for (int nt = 0; nt < 4; nt++) {
      bf16x8 b = *(const bf16x8*)(Bp + (size_t)(nt * 16 + m) * D2P + kc * 32);
      acc[nt] = mfma16(a, b, acc[nt]);
    }
  }
  const float* cnm = cn + mat * 64;
  float bv[4]; int bi[4];
  #pragma unroll
  for (int reg = 0; reg < 4; reg++) { bv[reg] = __builtin_inff(); bi[reg] = 1 << 30; }
  #pragma unroll
  for (int nt = 0; nt < 4; nt++) {
    int s = nt * 16 + m;
    float c = cnm[s & 63];
    #pragma unroll
    for (int reg = 0; reg < 4; reg++) {
      float d2 = (s < STY) ? (c - 2.0f * acc[nt][reg]) : __builtin_inff();
      if (d2 < bv[reg] || (d2 == bv[reg] && s < bi[reg])) { bv[reg] = d2; bi[reg] = s; }
    }
  }
  for (int off = 1; off < 16; off <<= 1) {
    #pragma unroll
    for (int reg = 0; reg < 4; reg++) {
      float ov = __shfl_xor(bv[reg], off);
      int   oi = __shfl_xor(bi[reg], off);
      if (ov < bv[reg] || (ov == bv[reg] && oi < bi[reg])) { bv[reg] = ov; bi[reg] = oi; }
    }
  }
  if (m == 0) {
    float* dst = mat ? stIK : stIJ;
    const float* ssm = ss + mat * 64;
    #pragma unroll
    for (int reg = 0; reg < 4; reg++) dst[r0 + q * 4 + reg] = ssm[bi[reg]];
  }
}

// ---------------- K4: loss3 (MFMA recon + squared error, HBM-bound) ----------------
// one wave = 16 d x 64 o tile; tiles: 46 x 777 x 2
__global__ __launch_bounds__(256) void k_loss3(
    const unsigned short* __restrict__ pnbf, const unsigned short* __restrict__ hbfT,
    const float* __restrict__ mp, const float* __restrict__ mn,
    double* __restrict__ l3sum) {
  const int NT_D = 46;
  const long NT_O = 777;
  const long TT = NT_D * NT_O;
  int w = threadIdx.x >> 6, lane = threadIdx.x & 63;
  int m = lane & 15, q = lane >> 4;
  long wid = (long)blockIdx.x * 4 + w;
  float local = 0.0f;
  if (wid < 2 * TT) {
    int mat = (wid >= TT) ? 1 : 0;
    long rem = wid - (long)mat * TT;
    int dt = (int)(rem % NT_D);
    int ot = (int)(rem / NT_D);
    int d0 = dt * 16, o0 = ot * 64;
    const unsigned short* A = pnbf + (size_t)mat * D2P * 64 + (size_t)(d0 + m) * 64 + q * 8;
    const unsigned short* B = hbfT + (size_t)mat * OUTP * 64 + q * 8;
    const float* M = mat ? mn : mp;
    floatx4 acc[4];
    #pragma unroll
    for (int nt = 0; nt < 4; nt++) acc[nt] = (floatx4){0.f, 0.f, 0.f, 0.f};
    #pragma unroll
    for (int kc = 0; kc < 2; kc++) {
      bf16x8 a = *(const bf16x8*)(A + kc * 32);
      #pragma unroll
      for (int nt = 0; nt < 4; nt++) {
        bf16x8 b = *(const bf16x8*)(B + (size_t)(o0 + nt * 16 + m) * 64 + kc * 32);
        acc[nt] = mfma16(a, b, acc[nt]);
      }
    }
    #pragma unroll
    for (int nt = 0; nt < 4; nt++) {
      int o = o0 + nt * 16 + m;
      #pragma unroll
      for (int reg = 0; reg < 4; reg++) {
        int d = d0 + q * 4 + reg;
        if (d < D2 && o < NOUT) {
          float e = M[(size_t)d * NOUT + o] - acc[nt][reg];
          local += e * e;
        }
      }
    }
  }
  for (int off = 32; off > 0; off >>= 1) local += __shfl_xor(local, off);
  if (lane == 0 && local != 0.0f) atomicAdd(l3sum, (double)local);
}

// ---------------- K5: final reductions ----------------
__global__ __launch_bounds__(256) void k_final(
    const float* __restrict__ sIJ, const float* __restrict__ sIK,
    const float* __restrict__ stIJ, const float* __restrict__ stIK,
    const double* __restrict__ l3sum, float* __restrict__ out) {
  int t = threadIdx.x;
  float l1 = 0.f, l2 = 0.f, ac = 0.f;
  for (int r = t; r < BATCH; r += 256) {
    float dij = sIJ[r] - sIK[r];
    l1 += softplusf(-dij);
    if (dij >= 0.0f) ac += 1.0f;
    float dst = stIJ[r] - stIK[r];
    l2 += softplusf(-dst);
  }
  __shared__ float sh1[4], sh2[4], sh3[4];
  for (int off = 32; off > 0; off >>= 1) {
    l1 += __shfl_xor(l1, off);
    l2 += __shfl_xor(l2, off);
    ac += __shfl_xor(ac, off);
  }
  if ((t & 63) == 0) { sh1[t >> 6] = l1; sh2[t >> 6] = l2; sh3[t >> 6] = ac; }
  __syncthreads();
  if (t == 0) {
    double L1 = 0, L2 = 0, AC = 0;
    for (int i = 0; i < 4; i++) { L1 += sh1[i]; L2 += sh2[i]; AC += sh3[i]; }
    L1 /= BATCH; L2 /= BATCH; AC /= BATCH;
    double L3 = l3sum[0] / ((double)D2 * (double)NOUT);
    out[0] = (float)(L1 + L2 + 0.1 * L3);
    out[1] = (float)L1;
    out[2] = (float)L2;
    out[3] = (float)L3;
    out[4] = (float)AC;
  }
}

extern "C" void kernel_launch(void* const* d_in, const int* in_sizes, int n_in,
                              void* d_out, int out_size, void* d_ws, size_t ws_size,
                              hipStream_t stream) {
  (void)in_sizes; (void)n_in; (void)out_size; (void)ws_size;
  const float* i_f  = (const float*)d_in[0];
  const float* j_f  = (const float*)d_in[1];
  const float* k_f  = (const float*)d_in[2];
  const float* W_t  = (const float*)d_in[3];
  const float* b_t  = (const float*)d_in[4];
  const float* W_b  = (const float*)d_in[5];
  const float* b_b  = (const float*)d_in[6];
  const float* P_n  = (const float*)d_in[7];
  const float* N_n  = (const float*)d_in[8];
  const float* H1   = (const float*)d_in[9];
  const float* H2   = (const float*)d_in[10];
  const float* Mp   = (const float*)d_in[11];
  const float* Mn   = (const float*)d_in[12];
  float* out = (float*)d_out;
  char* ws = (char*)d_ws;

  const size_t OFF_FBF   = 0;
  const size_t OFF_WBFT  = OFF_FBF  + (size_t)3 * BATCH * KP * 2;   // 37,748,736
  const size_t OFF_PNBF  = OFF_WBFT + (size_t)2 * HID * KP * 2;     // +393,216
  const size_t OFF_PNBFT = OFF_PNBF + (size_t)2 * D2P * 64 * 2;     // +196,608
  const size_t OFF_HBFT  = OFF_PNBFT+ (size_t)2 * 64 * D2P * 2;     // +196,608
  const size_t OFF_SIJ   = OFF_HBFT + (size_t)2 * OUTP * 64 * 2;    // +12,746,752 -> 51,281,920
  const size_t OFF_SIK   = OFF_SIJ  + (size_t)BATCH * 4;
  const size_t OFF_L3    = OFF_SIK  + (size_t)BATCH * 4;
  const size_t OFF_STIJ  = OFF_L3   + 64;
  const size_t OFF_STIK  = OFF_STIJ + (size_t)BATCH * 4;
  const size_t OFF_SS    = OFF_STIK + (size_t)BATCH * 4;
  const size_t OFF_CN    = OFF_SS   + 512;

  unsigned short* fbf   = (unsigned short*)(ws + OFF_FBF);
  unsigned short* wbfT  = (unsigned short*)(ws + OFF_WBFT);
  unsigned short* pnbf  = (unsigned short*)(ws + OFF_PNBF);
  unsigned short* pnbfT = (unsigned short*)(ws + OFF_PNBFT);
  unsigned short* hbfT  = (unsigned short*)(ws + OFF_HBFT);
  float*  sIJ  = (float*)(ws + OFF_SIJ);
  float*  sIK  = (float*)(ws + OFF_SIK);
  double* l3s  = (double*)(ws + OFF_L3);
  float*  stIJ = (float*)(ws + OFF_STIJ);
  float*  stIK = (float*)(ws + OFF_STIK);
  float*  ss   = (float*)(ws + OFF_SS);
  float*  cn   = (float*)(ws + OFF_CN);

  // zero: sIJ + sIK + loss3 accumulator (atomically accumulated)
  hipMemsetAsync(ws + OFF_SIJ, 0, (size_t)BATCH * 4 * 2 + 64, stream);

  k_conv_feat<<<dim3(BATCH, 3), 128, 0, stream>>>(i_f, j_f, k_f, fbf);
  k_conv_w   <<<dim3(HID, 2),  128, 0, stream>>>(W_t, W_b, wbfT);
  k_conv_pn  <<<dim3(D2P, 2),   64, 0, stream>>>(P_n, N_n, pnbf, pnbfT);
  k_conv_h   <<<dim3(195, 2),  256, 0, stream>>>(H1, H2, hbfT);

  k_style_scalar<<<120, 256, 0, stream>>>(P_n, N_n, W_t, b_t, W_b, b_b, ss, cn);
  k_emb         <<<dim3(BATCH / 64, 2), 256, 0, stream>>>(fbf, wbfT, b_t, b_b, sIJ, sIK);
  k_style_assign<<<BATCH / 32, 256, 0, stream>>>(fbf, pnbfT, cn, ss, stIJ, stIK);
  k_loss3       <<<17871, 256, 0, stream>>>(pnbf, hbfT, Mp, Mn, l3s);
  k_final       <<<1, 256, 0, stream>>>(sIJ, sIK, stIJ, stIK, l3s, out);
}

// Round 2
// 772.892 us; speedup vs baseline: 1.8974x; 1.8974x over previous
//
#include <hip/hip_runtime.h>
#include <math.h>

#define BATCH 16384
#define IND   362
#define KP    384      // per-feature K padded to 384 (12 x 32)
#define HID   256
#define STY   60
#define NOUT  49710
#define OUTP  49792    // padded o-stride for hbfT
#define D2    724
#define D2P   768
#define L3_BLOCKS 17871   // k_loss3 grid: 17871 blocks x 4 waves = 71484 = 2*46*777 tiles

typedef __bf16 bf16x8 __attribute__((ext_vector_type(8)));
typedef float  floatx4 __attribute__((ext_vector_type(4)));

__device__ inline floatx4 mfma16(bf16x8 a, bf16x8 b, floatx4 c) {
  return __builtin_amdgcn_mfma_f32_16x16x32_bf16(a, b, c, 0, 0, 0);
}

__device__ inline unsigned short f32_to_bf16(float x) {
  unsigned int u = __float_as_uint(x);
  unsigned int r = (u + 0x7FFFu + ((u >> 16) & 1u)) >> 16;
  return (unsigned short)r;
}

__device__ inline float sigm_fast(float x) { return 1.0f / (1.0f + __expf(-x)); }
__device__ inline float softplusf(float z) { return fmaxf(z, 0.0f) + log1pf(expf(-fabsf(z))); }

// ---------------- convert kernels ----------------

// features f32 (BATCH x 362) -> bf16 (BATCH x 384, zero-padded), 3 arrays
__global__ void k_conv_feat(const float* __restrict__ fi, const float* __restrict__ fj,
                            const float* __restrict__ fk, unsigned short* __restrict__ fbf) {
  int row = blockIdx.x;
  int f = blockIdx.y;
  const float* src = (f == 0) ? fi : (f == 1 ? fj : fk);
  unsigned short* dst = fbf + ((size_t)f * BATCH + row) * KP;
  for (int d = threadIdx.x; d < KP; d += blockDim.x) {
    float v = (d < IND) ? src[(size_t)row * IND + d] : 0.0f;
    dst[d] = f32_to_bf16(v);
  }
}

// W (362x256) -> wbfT [2][256][384] bf16 (transposed, k-padded)
__global__ void k_conv_w(const float* __restrict__ Wt, const float* __restrict__ Wb,
                         unsigned short* __restrict__ wbfT) {
  int h = blockIdx.x;
  int m = blockIdx.y;
  const float* W = m ? Wb : Wt;
  unsigned short* dst = wbfT + ((size_t)m * HID + h) * KP;
  for (int k = threadIdx.x; k < KP; k += blockDim.x) {
    float v = (k < IND) ? W[(size_t)k * HID + h] : 0.0f;
    dst[k] = f32_to_bf16(v);
  }
}

// P/N (724x60) relu -> pnbf [2][768][64] ([d][s]) and pnbfT [2][64][768] ([s][k], 384-split padding)
__global__ void k_conv_pn(const float* __restrict__ P, const float* __restrict__ N,
                          unsigned short* __restrict__ pnbf, unsigned short* __restrict__ pnbfT) {
  int d = blockIdx.x;   // 0..767
  int m = blockIdx.y;
  int s = threadIdx.x;  // 0..63
  const float* M = m ? N : P;
  float v = (d < D2 && s < STY) ? fmaxf(M[(size_t)d * STY + s], 0.0f) : 0.0f;
  unsigned short b = f32_to_bf16(v);
  pnbf[((size_t)m * D2P + d) * 64 + s] = b;
  // bijective pad mapping: d<362 -> k=d ; 362<=d<724 -> k=d+22 ; 724<=d<746 -> k=d-362 (pad) ; else k=d (pad)
  int k = (d < IND) ? d : (d < D2 ? d + 22 : (d < 746 ? d - IND : d));
  pnbfT[((size_t)m * 64 + s) * D2P + k] = b;
}

// H1/H2 (60x49710) relu -> hbfT [2][49792][64] bf16 (transposed [o][k])
__global__ void k_conv_h(const float* __restrict__ H1, const float* __restrict__ H2,
                         unsigned short* __restrict__ hbfT) {
  int o = blockIdx.x * 256 + threadIdx.x;
  int m = blockIdx.y;
  if (o >= OUTP) return;
  const float* H = m ? H2 : H1;
  unsigned short* dst = hbfT + ((size_t)m * OUTP + o) * 64;
  bool ov = (o < NOUT);
  #pragma unroll
  for (int g = 0; g < 8; g++) {
    unsigned int wv[4];
    #pragma unroll
    for (int e = 0; e < 4; e++) {
      int kk = g * 8 + e * 2;
      float lo = (ov && kk < STY)     ? fmaxf(H[(size_t)kk * NOUT + o], 0.0f) : 0.0f;
      float hi = (ov && kk + 1 < STY) ? fmaxf(H[(size_t)(kk + 1) * NOUT + o], 0.0f) : 0.0f;
      wv[e] = (unsigned)f32_to_bf16(lo) | ((unsigned)f32_to_bf16(hi) << 16);
    }
    uint4 v; v.x = wv[0]; v.y = wv[1]; v.z = wv[2]; v.w = wv[3];
    *(uint4*)(dst + g * 8) = v;
  }
}

// ---------------- K1: per-style scalar scores + column norms (fp32 exact) ----------------
__global__ __launch_bounds__(256) void k_style_scalar(
    const float* __restrict__ Pn, const float* __restrict__ Nn,
    const float* __restrict__ Wt, const float* __restrict__ btop,
    const float* __restrict__ Wb, const float* __restrict__ bbot,
    float* __restrict__ ss, float* __restrict__ cn) {
  int s  = blockIdx.x % STY;
  int mt = blockIdx.x / STY;
  const float* M = mt ? Nn : Pn;
  __shared__ float sel[D2];
  __shared__ float shr[4];
  int t = threadIdx.x;
  float cnp = 0.0f;
  for (int d = t; d < D2; d += 256) {
    float v = fmaxf(M[(size_t)d * STY + s], 0.0f);
    sel[d] = v;
    cnp += v * v;
  }
  __syncthreads();
  float at = btop[t], ab = bbot[t];
  for (int d = 0; d < IND; d++) at = fmaf(sel[d],        Wt[(size_t)d * HID + t], at);
  for (int d = 0; d < IND; d++) ab = fmaf(sel[IND + d],  Wb[(size_t)d * HID + t], ab);
  float prod = (1.0f / (1.0f + expf(-at))) * (1.0f / (1.0f + expf(-ab)));
  for (int off = 32; off > 0; off >>= 1) prod += __shfl_xor(prod, off);
  if ((t & 63) == 0) shr[t >> 6] = prod;
  __syncthreads();
  if (t == 0) ss[mt * 64 + s] = shr[0] + shr[1] + shr[2] + shr[3];
  __syncthreads();
  for (int off = 32; off > 0; off >>= 1) cnp += __shfl_xor(cnp, off);
  if ((t & 63) == 0) shr[t >> 6] = cnp;
  __syncthreads();
  if (t == 0) cn[mt * 64 + s] = shr[0] + shr[1] + shr[2] + shr[3];
}

// ---------------- K2: embedding GEMMs (MFMA) + ij/ik scores ----------------
// wave = 16 rows x 128 hidden ; grid (BATCH/64, 2)
__global__ __launch_bounds__(256) void k_emb(
    const unsigned short* __restrict__ fbf, const unsigned short* __restrict__ wbfT,
    const float* __restrict__ btop, const float* __restrict__ bbot,
    float* __restrict__ sIJ, float* __restrict__ sIK) {
  int w = threadIdx.x >> 6, lane = threadIdx.x & 63;
  int m = lane & 15, q = lane >> 4;
  int r0 = blockIdx.x * 64 + w * 16;
  int hb = blockIdx.y * 128;
  const unsigned short* fi = fbf + (size_t)(r0 + m) * KP + q * 8;
  const unsigned short* fj = fi + (size_t)BATCH * KP;
  const unsigned short* fk = fj + (size_t)BATCH * KP;
  floatx4 accI[8], accJ[8], accK[8];
  #pragma unroll
  for (int nt = 0; nt < 8; nt++) {
    accI[nt] = (floatx4){0.f, 0.f, 0.f, 0.f};
    accJ[nt] = (floatx4){0.f, 0.f, 0.f, 0.f};
    accK[nt] = (floatx4){0.f, 0.f, 0.f, 0.f};
  }
  for (int kc = 0; kc < 12; kc++) {
    bf16x8 ai = *(const bf16x8*)(fi + kc * 32);
    bf16x8 aj = *(const bf16x8*)(fj + kc * 32);
    bf16x8 ak = *(const bf16x8*)(fk + kc * 32);
    #pragma unroll
    for (int nt = 0; nt < 8; nt++) {
      int n = hb + nt * 16 + m;
      const unsigned short* wp = wbfT + (size_t)n * KP + kc * 32 + q * 8;
      bf16x8 bt8 = *(const bf16x8*)(wp);
      bf16x8 bb8 = *(const bf16x8*)(wp + (size_t)HID * KP);
      accI[nt] = mfma16(ai, bt8, accI[nt]);
      accJ[nt] = mfma16(aj, bb8, accJ[nt]);
      accK[nt] = mfma16(ak, bb8, accK[nt]);
    }
  }
  float sij[4] = {0.f, 0.f, 0.f, 0.f}, sik[4] = {0.f, 0.f, 0.f, 0.f};
  #pragma unroll
  for (int nt = 0; nt < 8; nt++) {
    int n = hb + nt * 16 + m;
    float vbt = btop[n], vbb = bbot[n];
    #pragma unroll
    for (int reg = 0; reg < 4; reg++) {
      float ti = sigm_fast(accI[nt][reg] + vbt);
      float tj = sigm_fast(accJ[nt][reg] + vbb);
      float tk = sigm_fast(accK[nt][reg] + vbb);
      sij[reg] += ti * tj;
      sik[reg] += ti * tk;
    }
  }
  #pragma unroll
  for (int reg = 0; reg < 4; reg++) {
    for (int off = 1; off < 16; off <<= 1) {
      sij[reg] += __shfl_xor(sij[reg], off);
      sik[reg] += __shfl_xor(sik[reg], off);
    }
  }
  if (m == 0) {
    #pragma unroll
    for (int reg = 0; reg < 4; reg++) {
      int row = r0 + q * 4 + reg;
      atomicAdd(&sIJ[row], sij[reg]);
      atomicAdd(&sIK[row], sik[reg]);
    }
  }
}

// ---------------- K3: style argmin + gather (MFMA) ----------------
__global__ __launch_bounds__(256) void k_style_assign(
    const unsigned short* __restrict__ fbf, const unsigned short* __restrict__ pnbfT,
    const float* __restrict__ cn, const float* __restrict__ ss,
    float* __restrict__ stIJ, float* __restrict__ stIK) {
  int w = threadIdx.x >> 6, lane = threadIdx.x & 63;
  int m = lane & 15, q = lane >> 4;
  int mat = w & 1;
  int r0 = blockIdx.x * 32 + (w >> 1) * 16;
  const unsigned short* fA = fbf + (size_t)(r0 + m) * KP + q * 8;              // i
  const unsigned short* fB = fA + (size_t)(1 + mat) * BATCH * KP;              // j or k
  const unsigned short* Bp = pnbfT + (size_t)mat * 64 * D2P + q * 8;
  floatx4 acc[4];
  #pragma unroll
  for (int nt = 0; nt < 4; nt++) acc[nt] = (floatx4){0.f, 0.f, 0.f, 0.f};
  for (int kc = 0; kc < 24; kc++) {
    bf16x8 a = (kc < 12) ? *(const bf16x8*)(fA + kc * 32)
                         : *(const bf16x8*)(fB + (kc - 12) * 32);
    #pragma unroll
    for (int nt = 0; nt < 4; nt++) {
      bf16x8 b = *(const bf16x8*)(Bp + (size_t)(nt * 16 + m) * D2P + kc * 32);
      acc[nt] = mfma16(a, b, acc[nt]);
    }
  }
  const float* cnm = cn + mat * 64;
  float bv[4]; int bi[4];
  #pragma unroll
  for (int reg = 0; reg < 4; reg++) { bv[reg] = __builtin_inff(); bi[reg] = 1 << 30; }
  #pragma unroll
  for (int nt = 0; nt < 4; nt++) {
    int s = nt * 16 + m;
    float c = cnm[s & 63];
    #pragma unroll
    for (int reg = 0; reg < 4; reg++) {
      float d2 = (s < STY) ? (c - 2.0f * acc[nt][reg]) : __builtin_inff();
      if (d2 < bv[reg] || (d2 == bv[reg] && s < bi[reg])) { bv[reg] = d2; bi[reg] = s; }
    }
  }
  for (int off = 1; off < 16; off <<= 1) {
    #pragma unroll
    for (int reg = 0; reg < 4; reg++) {
      float ov = __shfl_xor(bv[reg], off);
      int   oi = __shfl_xor(bi[reg], off);
      if (ov < bv[reg] || (ov == bv[reg] && oi < bi[reg])) { bv[reg] = ov; bi[reg] = oi; }
    }
  }
  if (m == 0) {
    float* dst = mat ? stIK : stIJ;
    const float* ssm = ss + mat * 64;
    #pragma unroll
    for (int reg = 0; reg < 4; reg++) dst[r0 + q * 4 + reg] = ssm[bi[reg]];
  }
}

// ---------------- K4: loss3 (MFMA recon + squared error, HBM-bound) ----------------
// one wave = 16 d x 64 o tile; tiles: 46 x 777 x 2; per-block fp32 partial (NO atomics)
__global__ __launch_bounds__(256) void k_loss3(
    const unsigned short* __restrict__ pnbf, const unsigned short* __restrict__ hbfT,
    const float* __restrict__ mp, const float* __restrict__ mn,
    float* __restrict__ partial) {
  const int NT_D = 46;
  const long NT_O = 777;
  const long TT = NT_D * NT_O;
  int w = threadIdx.x >> 6, lane = threadIdx.x & 63;
  int m = lane & 15, q = lane >> 4;
  long wid = (long)blockIdx.x * 4 + w;
  float local = 0.0f;
  {
    int mat = (wid >= TT) ? 1 : 0;
    long rem = wid - (long)mat * TT;
    int dt = (int)(rem % NT_D);
    int ot = (int)(rem / NT_D);
    int d0 = dt * 16, o0 = ot * 64;
    const unsigned short* A = pnbf + (size_t)mat * D2P * 64 + (size_t)(d0 + m) * 64 + q * 8;
    const unsigned short* B = hbfT + (size_t)mat * OUTP * 64 + q * 8;
    const float* M = mat ? mn : mp;
    floatx4 acc[4];
    #pragma unroll
    for (int nt = 0; nt < 4; nt++) acc[nt] = (floatx4){0.f, 0.f, 0.f, 0.f};
    #pragma unroll
    for (int kc = 0; kc < 2; kc++) {
      bf16x8 a = *(const bf16x8*)(A + kc * 32);
      #pragma unroll
      for (int nt = 0; nt < 4; nt++) {
        bf16x8 b = *(const bf16x8*)(B + (size_t)(o0 + nt * 16 + m) * 64 + kc * 32);
        acc[nt] = mfma16(a, b, acc[nt]);
      }
    }
    #pragma unroll
    for (int nt = 0; nt < 4; nt++) {
      int o = o0 + nt * 16 + m;
      #pragma unroll
      for (int reg = 0; reg < 4; reg++) {
        int d = d0 + q * 4 + reg;
        if (d < D2 && o < NOUT) {
          float e = M[(size_t)d * NOUT + o] - acc[nt][reg];
          local += e * e;
        }
      }
    }
  }
  for (int off = 32; off > 0; off >>= 1) local += __shfl_xor(local, off);
  __shared__ float shp[4];
  if (lane == 0) shp[w] = local;
  __syncthreads();
  if (threadIdx.x == 0) partial[blockIdx.x] = shp[0] + shp[1] + shp[2] + shp[3];
}

// ---------------- K5: final reductions ----------------
__global__ __launch_bounds__(256) void k_final(
    const float* __restrict__ sIJ, const float* __restrict__ sIK,
    const float* __restrict__ stIJ, const float* __restrict__ stIK,
    const float* __restrict__ l3partial, float* __restrict__ out) {
  int t = threadIdx.x;
  float l1 = 0.f, l2 = 0.f, ac = 0.f;
  for (int r = t; r < BATCH; r += 256) {
    float dij = sIJ[r] - sIK[r];
    l1 += softplusf(-dij);
    if (dij >= 0.0f) ac += 1.0f;
    float dst = stIJ[r] - stIK[r];
    l2 += softplusf(-dst);
  }
  double l3 = 0.0;
  for (int p = t; p < L3_BLOCKS; p += 256) l3 += (double)l3partial[p];
  __shared__ float sh1[4], sh2[4], sh3[4];
  __shared__ double sh4[4];
  for (int off = 32; off > 0; off >>= 1) {
    l1 += __shfl_xor(l1, off);
    l2 += __shfl_xor(l2, off);
    ac += __shfl_xor(ac, off);
    l3 += __shfl_xor(l3, off);
  }
  if ((t & 63) == 0) { sh1[t >> 6] = l1; sh2[t >> 6] = l2; sh3[t >> 6] = ac; sh4[t >> 6] = l3; }
  __syncthreads();
  if (t == 0) {
    double L1 = 0, L2 = 0, AC = 0, L3 = 0;
    for (int i = 0; i < 4; i++) { L1 += sh1[i]; L2 += sh2[i]; AC += sh3[i]; L3 += sh4[i]; }
    L1 /= BATCH; L2 /= BATCH; AC /= BATCH;
    L3 /= ((double)D2 * (double)NOUT);
    out[0] = (float)(L1 + L2 + 0.1 * L3);
    out[1] = (float)L1;
    out[2] = (float)L2;
    out[3] = (float)L3;
    out[4] = (float)AC;
  }
}

extern "C" void kernel_launch(void* const* d_in, const int* in_sizes, int n_in,
                              void* d_out, int out_size, void* d_ws, size_t ws_size,
                              hipStream_t stream) {
  (void)in_sizes; (void)n_in; (void)out_size; (void)ws_size;
  const float* i_f  = (const float*)d_in[0];
  const float* j_f  = (const float*)d_in[1];
  const float* k_f  = (const float*)d_in[2];
  const float* W_t  = (const float*)d_in[3];
  const float* b_t  = (const float*)d_in[4];
  const float* W_b  = (const float*)d_in[5];
  const float* b_b  = (const float*)d_in[6];
  const float* P_n  = (const float*)d_in[7];
  const float* N_n  = (const float*)d_in[8];
  const float* H1   = (const float*)d_in[9];
  const float* H2   = (const float*)d_in[10];
  const float* Mp   = (const float*)d_in[11];
  const float* Mn   = (const float*)d_in[12];
  float* out = (float*)d_out;
  char* ws = (char*)d_ws;

  const size_t OFF_FBF   = 0;
  const size_t OFF_WBFT  = OFF_FBF  + (size_t)3 * BATCH * KP * 2;   // 37,748,736
  const size_t OFF_PNBF  = OFF_WBFT + (size_t)2 * HID * KP * 2;
  const size_t OFF_PNBFT = OFF_PNBF + (size_t)2 * D2P * 64 * 2;
  const size_t OFF_HBFT  = OFF_PNBFT+ (size_t)2 * 64 * D2P * 2;
  const size_t OFF_SIJ   = OFF_HBFT + (size_t)2 * OUTP * 64 * 2;
  const size_t OFF_SIK   = OFF_SIJ  + (size_t)BATCH * 4;
  const size_t OFF_STIJ  = OFF_SIK  + (size_t)BATCH * 4;
  const size_t OFF_STIK  = OFF_STIJ + (size_t)BATCH * 4;
  const size_t OFF_SS    = OFF_STIK + (size_t)BATCH * 4;
  const size_t OFF_CN    = OFF_SS   + 512;
  const size_t OFF_L3P   = OFF_CN   + 512;   // L3_BLOCKS floats

  unsigned short* fbf   = (unsigned short*)(ws + OFF_FBF);
  unsigned short* wbfT  = (unsigned short*)(ws + OFF_WBFT);
  unsigned short* pnbf  = (unsigned short*)(ws + OFF_PNBF);
  unsigned short* pnbfT = (unsigned short*)(ws + OFF_PNBFT);
  unsigned short* hbfT  = (unsigned short*)(ws + OFF_HBFT);
  float*  sIJ  = (float*)(ws + OFF_SIJ);
  float*  sIK  = (float*)(ws + OFF_SIK);
  float*  stIJ = (float*)(ws + OFF_STIJ);
  float*  stIK = (float*)(ws + OFF_STIK);
  float*  ss   = (float*)(ws + OFF_SS);
  float*  cn   = (float*)(ws + OFF_CN);
  float*  l3p  = (float*)(ws + OFF_L3P);

  // zero: sIJ + sIK (atomically accumulated by k_emb)
  hipMemsetAsync(ws + OFF_SIJ, 0, (size_t)BATCH * 4 * 2, stream);

  k_conv_feat<<<dim3(BATCH, 3), 128, 0, stream>>>(i_f, j_f, k_f, fbf);
  k_conv_w   <<<dim3(HID, 2),  128, 0, stream>>>(W_t, W_b, wbfT);
  k_conv_pn  <<<dim3(D2P, 2),   64, 0, stream>>>(P_n, N_n, pnbf, pnbfT);
  k_conv_h   <<<dim3(195, 2),  256, 0, stream>>>(H1, H2, hbfT);

  k_style_scalar<<<120, 256, 0, stream>>>(P_n, N_n, W_t, b_t, W_b, b_b, ss, cn);
  k_emb         <<<dim3(BATCH / 64, 2), 256, 0, stream>>>(fbf, wbfT, b_t, b_b, sIJ, sIK);
  k_style_assign<<<BATCH / 32, 256, 0, stream>>>(fbf, pnbfT, cn, ss, stIJ, stIK);
  k_loss3       <<<L3_BLOCKS, 256, 0, stream>>>(pnbf, hbfT, Mp, Mn, l3p);
  k_final       <<<1, 256, 0, stream>>>(sIJ, sIK, stIJ, stIK, l3p, out);
}

// Round 3
// 674.370 us; speedup vs baseline: 2.1746x; 1.1461x over previous
//
#include <hip/hip_runtime.h>
#include <math.h>

#define BATCH 16384
#define IND   362
#define KP    384      // per-feature K padded to 384 (12 x 32)
#define HID   256
#define STY   60
#define NOUT  49710
#define OUTP  49792    // padded o-stride for hbfT
#define D2    724
#define D2P   768
#define NSTRIP 777     // ceil(NOUT/64)
#define L3_BLOCKS (2 * NSTRIP)   // k_loss3 grid: one block per (mat, o-strip)

typedef __bf16 bf16x8 __attribute__((ext_vector_type(8)));
typedef float  floatx4 __attribute__((ext_vector_type(4)));
typedef float  floatx2 __attribute__((ext_vector_type(2)));

__device__ inline floatx4 mfma16(bf16x8 a, bf16x8 b, floatx4 c) {
  return __builtin_amdgcn_mfma_f32_16x16x32_bf16(a, b, c, 0, 0, 0);
}

__device__ inline unsigned short f32_to_bf16(float x) {
  unsigned int u = __float_as_uint(x);
  unsigned int r = (u + 0x7FFFu + ((u >> 16) & 1u)) >> 16;
  return (unsigned short)r;
}

__device__ inline float sigm_fast(float x) { return 1.0f / (1.0f + __expf(-x)); }
__device__ inline float softplusf(float z) { return fmaxf(z, 0.0f) + log1pf(expf(-fabsf(z))); }

// ---------------- convert kernels ----------------

// features f32 (BATCH x 362) -> bf16 (BATCH x 384, zero-padded), 3 arrays
// unit = (f, row, g): g in [0,48) handles dims 8g..8g+7; uint4 stores
__global__ __launch_bounds__(256) void k_conv_feat(
    const float* __restrict__ fi, const float* __restrict__ fj,
    const float* __restrict__ fk, unsigned short* __restrict__ fbf) {
  long u = (long)blockIdx.x * 256 + threadIdx.x;
  const long TOT = (long)3 * BATCH * 48;
  if (u >= TOT) return;
  int g = (int)(u % 48);
  long rf = u / 48;
  int row = (int)(rf % BATCH);
  int f = (int)(rf / BATCH);
  const float* src = (f == 0) ? fi : (f == 1 ? fj : fk);
  int d0 = g * 8;
  const float* sp = src + (size_t)row * IND + d0;
  unsigned int wv[4];
  #pragma unroll
  for (int e = 0; e < 4; e++) {
    int dd = d0 + 2 * e;
    float lo = (dd < IND)     ? sp[2 * e]     : 0.0f;
    float hi = (dd + 1 < IND) ? sp[2 * e + 1] : 0.0f;
    wv[e] = (unsigned)f32_to_bf16(lo) | ((unsigned)f32_to_bf16(hi) << 16);
  }
  uint4 v; v.x = wv[0]; v.y = wv[1]; v.z = wv[2]; v.w = wv[3];
  *(uint4*)(fbf + ((size_t)f * BATCH + row) * KP + d0) = v;
}

// W (362x256) -> wbfT [2][256][384] bf16 (transposed, k-padded)
__global__ void k_conv_w(const float* __restrict__ Wt, const float* __restrict__ Wb,
                         unsigned short* __restrict__ wbfT) {
  int h = blockIdx.x;
  int m = blockIdx.y;
  const float* W = m ? Wb : Wt;
  unsigned short* dst = wbfT + ((size_t)m * HID + h) * KP;
  for (int k = threadIdx.x; k < KP; k += blockDim.x) {
    float v = (k < IND) ? W[(size_t)k * HID + h] : 0.0f;
    dst[k] = f32_to_bf16(v);
  }
}

// P/N (724x60) relu -> pnbf [2][768][64] ([d][s]) and pnbfT [2][64][768] ([s][k], 384-split padding)
__global__ void k_conv_pn(const float* __restrict__ P, const float* __restrict__ N,
                          unsigned short* __restrict__ pnbf, unsigned short* __restrict__ pnbfT) {
  int d = blockIdx.x;   // 0..767
  int m = blockIdx.y;
  int s = threadIdx.x;  // 0..63
  const float* M = m ? N : P;
  float v = (d < D2 && s < STY) ? fmaxf(M[(size_t)d * STY + s], 0.0f) : 0.0f;
  unsigned short b = f32_to_bf16(v);
  pnbf[((size_t)m * D2P + d) * 64 + s] = b;
  // bijective pad mapping: d<362 -> k=d ; 362<=d<724 -> k=d+22 ; 724<=d<746 -> k=d-362 (pad) ; else k=d (pad)
  int k = (d < IND) ? d : (d < D2 ? d + 22 : (d < 746 ? d - IND : d));
  pnbfT[((size_t)m * 64 + s) * D2P + k] = b;
}

// H1/H2 (60x49710) relu -> hbfT [2][49792][64] bf16 (transposed [o][k])
__global__ void k_conv_h(const float* __restrict__ H1, const float* __restrict__ H2,
                         unsigned short* __restrict__ hbfT) {
  int o = blockIdx.x * 256 + threadIdx.x;
  int m = blockIdx.y;
  if (o >= OUTP) return;
  const float* H = m ? H2 : H1;
  unsigned short* dst = hbfT + ((size_t)m * OUTP + o) * 64;
  bool ov = (o < NOUT);
  #pragma unroll
  for (int g = 0; g < 8; g++) {
    unsigned int wv[4];
    #pragma unroll
    for (int e = 0; e < 4; e++) {
      int kk = g * 8 + e * 2;
      float lo = (ov && kk < STY)     ? fmaxf(H[(size_t)kk * NOUT + o], 0.0f) : 0.0f;
      float hi = (ov && kk + 1 < STY) ? fmaxf(H[(size_t)(kk + 1) * NOUT + o], 0.0f) : 0.0f;
      wv[e] = (unsigned)f32_to_bf16(lo) | ((unsigned)f32_to_bf16(hi) << 16);
    }
    uint4 v; v.x = wv[0]; v.y = wv[1]; v.z = wv[2]; v.w = wv[3];
    *(uint4*)(dst + g * 8) = v;
  }
}

// ---------------- K1: per-style scalar scores + column norms (fp32 exact) ----------------
__global__ __launch_bounds__(256) void k_style_scalar(
    const float* __restrict__ Pn, const float* __restrict__ Nn,
    const float* __restrict__ Wt, const float* __restrict__ btop,
    const float* __restrict__ Wb, const float* __restrict__ bbot,
    float* __restrict__ ss, float* __restrict__ cn) {
  int s  = blockIdx.x % STY;
  int mt = blockIdx.x / STY;
  const float* M = mt ? Nn : Pn;
  __shared__ float sel[D2];
  __shared__ float shr[4];
  int t = threadIdx.x;
  float cnp = 0.0f;
  for (int d = t; d < D2; d += 256) {
    float v = fmaxf(M[(size_t)d * STY + s], 0.0f);
    sel[d] = v;
    cnp += v * v;
  }
  __syncthreads();
  float at = btop[t], ab = bbot[t];
  for (int d = 0; d < IND; d++) at = fmaf(sel[d],        Wt[(size_t)d * HID + t], at);
  for (int d = 0; d < IND; d++) ab = fmaf(sel[IND + d],  Wb[(size_t)d * HID + t], ab);
  float prod = (1.0f / (1.0f + expf(-at))) * (1.0f / (1.0f + expf(-ab)));
  for (int off = 32; off > 0; off >>= 1) prod += __shfl_xor(prod, off);
  if ((t & 63) == 0) shr[t >> 6] = prod;
  __syncthreads();
  if (t == 0) ss[mt * 64 + s] = shr[0] + shr[1] + shr[2] + shr[3];
  __syncthreads();
  for (int off = 32; off > 0; off >>= 1) cnp += __shfl_xor(cnp, off);
  if ((t & 63) == 0) shr[t >> 6] = cnp;
  __syncthreads();
  if (t == 0) cn[mt * 64 + s] = shr[0] + shr[1] + shr[2] + shr[3];
}

// ---------------- K2: embedding GEMMs (MFMA) + ij/ik scores ----------------
__global__ __launch_bounds__(256) void k_emb(
    const unsigned short* __restrict__ fbf, const unsigned short* __restrict__ wbfT,
    const float* __restrict__ btop, const float* __restrict__ bbot,
    float* __restrict__ sIJ, float* __restrict__ sIK) {
  int w = threadIdx.x >> 6, lane = threadIdx.x & 63;
  int m = lane & 15, q = lane >> 4;
  int r0 = blockIdx.x * 64 + w * 16;
  int hb = blockIdx.y * 128;
  const unsigned short* fi = fbf + (size_t)(r0 + m) * KP + q * 8;
  const unsigned short* fj = fi + (size_t)BATCH * KP;
  const unsigned short* fk = fj + (size_t)BATCH * KP;
  floatx4 accI[8], accJ[8], accK[8];
  #pragma unroll
  for (int nt = 0; nt < 8; nt++) {
    accI[nt] = (floatx4){0.f, 0.f, 0.f, 0.f};
    accJ[nt] = (floatx4){0.f, 0.f, 0.f, 0.f};
    accK[nt] = (floatx4){0.f, 0.f, 0.f, 0.f};
  }
  for (int kc = 0; kc < 12; kc++) {
    bf16x8 ai = *(const bf16x8*)(fi + kc * 32);
    bf16x8 aj = *(const bf16x8*)(fj + kc * 32);
    bf16x8 ak = *(const bf16x8*)(fk + kc * 32);
    #pragma unroll
    for (int nt = 0; nt < 8; nt++) {
      int n = hb + nt * 16 + m;
      const unsigned short* wp = wbfT + (size_t)n * KP + kc * 32 + q * 8;
      bf16x8 bt8 = *(const bf16x8*)(wp);
      bf16x8 bb8 = *(const bf16x8*)(wp + (size_t)HID * KP);
      accI[nt] = mfma16(ai, bt8, accI[nt]);
      accJ[nt] = mfma16(aj, bb8, accJ[nt]);
      accK[nt] = mfma16(ak, bb8, accK[nt]);
    }
  }
  float sij[4] = {0.f, 0.f, 0.f, 0.f}, sik[4] = {0.f, 0.f, 0.f, 0.f};
  #pragma unroll
  for (int nt = 0; nt < 8; nt++) {
    int n = hb + nt * 16 + m;
    float vbt = btop[n], vbb = bbot[n];
    #pragma unroll
    for (int reg = 0; reg < 4; reg++) {
      float ti = sigm_fast(accI[nt][reg] + vbt);
      float tj = sigm_fast(accJ[nt][reg] + vbb);
      float tk = sigm_fast(accK[nt][reg] + vbb);
      sij[reg] += ti * tj;
      sik[reg] += ti * tk;
    }
  }
  #pragma unroll
  for (int reg = 0; reg < 4; reg++) {
    for (int off = 1; off < 16; off <<= 1) {
      sij[reg] += __shfl_xor(sij[reg], off);
      sik[reg] += __shfl_xor(sik[reg], off);
    }
  }
  if (m == 0) {
    #pragma unroll
    for (int reg = 0; reg < 4; reg++) {
      int row = r0 + q * 4 + reg;
      atomicAdd(&sIJ[row], sij[reg]);
      atomicAdd(&sIK[row], sik[reg]);
    }
  }
}

// ---------------- K3: style argmin + gather (MFMA) ----------------
__global__ __launch_bounds__(256) void k_style_assign(
    const unsigned short* __restrict__ fbf, const unsigned short* __restrict__ pnbfT,
    const float* __restrict__ cn, const float* __restrict__ ss,
    float* __restrict__ stIJ, float* __restrict__ stIK) {
  int w = threadIdx.x >> 6, lane = threadIdx.x & 63;
  int m = lane & 15, q = lane >> 4;
  int mat = w & 1;
  int r0 = blockIdx.x * 32 + (w >> 1) * 16;
  const unsigned short* fA = fbf + (size_t)(r0 + m) * KP + q * 8;              // i
  const unsigned short* fB = fA + (size_t)(1 + mat) * BATCH * KP;              // j or k
  const unsigned short* Bp = pnbfT + (size_t)mat * 64 * D2P + q * 8;
  floatx4 acc[4];
  #pragma unroll
  for (int nt = 0; nt < 4; nt++) acc[nt] = (floatx4){0.f, 0.f, 0.f, 0.f};
  for (int kc = 0; kc < 24; kc++) {
    bf16x8 a = (kc < 12) ? *(const bf16x8*)(fA + kc * 32)
                         : *(const bf16x8*)(fB + (kc - 12) * 32);
    #pragma unroll
    for (int nt = 0; nt < 4; nt++) {
      bf16x8 b = *(const bf16x8*)(Bp + (size_t)(nt * 16 + m) * D2P + kc * 32);
      acc[nt] = mfma16(a, b, acc[nt]);
    }
  }
  const float* cnm = cn + mat * 64;
  float bv[4]; int bi[4];
  #pragma unroll
  for (int reg = 0; reg < 4; reg++) { bv[reg] = __builtin_inff(); bi[reg] = 1 << 30; }
  #pragma unroll
  for (int nt = 0; nt < 4; nt++) {
    int s = nt * 16 + m;
    float c = cnm[s & 63];
    #pragma unroll
    for (int reg = 0; reg < 4; reg++) {
      float d2 = (s < STY) ? (c - 2.0f * acc[nt][reg]) : __builtin_inff();
      if (d2 < bv[reg] || (d2 == bv[reg] && s < bi[reg])) { bv[reg] = d2; bi[reg] = s; }
    }
  }
  for (int off = 1; off < 16; off <<= 1) {
    #pragma unroll
    for (int reg = 0; reg < 4; reg++) {
      float ov = __shfl_xor(bv[reg], off);
      int   oi = __shfl_xor(bi[reg], off);
      if (ov < bv[reg] || (ov == bv[reg] && oi < bi[reg])) { bv[reg] = ov; bi[reg] = oi; }
    }
  }
  if (m == 0) {
    float* dst = mat ? stIK : stIJ;
    const float* ssm = ss + mat * 64;
    #pragma unroll
    for (int reg = 0; reg < 4; reg++) dst[r0 + q * 4 + reg] = ssm[bi[reg]];
  }
}

// ---------------- K4: loss3 — one block per (mat, 64-o strip); wave w covers d-tiles [12w, 12w+ntile) ----------------
// hbfT strip held in registers (read once per block); M read as aligned float2 pairs.
// MFMA roles: A = hbfT rows (o = M-dim), B = pnbf (d = N-dim); acc row = o, col = d.
__global__ __launch_bounds__(256) void k_loss3(
    const unsigned short* __restrict__ pnbf, const unsigned short* __restrict__ hbfT,
    const float* __restrict__ mp, const float* __restrict__ mn,
    float* __restrict__ partial) {
  int w = threadIdx.x >> 6, lane = threadIdx.x & 63;
  int m = lane & 15, q = lane >> 4;
  int strip = blockIdx.x % NSTRIP;
  int mat   = blockIdx.x / NSTRIP;
  int o0 = strip * 64;
  const float* M = mat ? mn : mp;
  const unsigned short* Hb = hbfT + (size_t)mat * OUTP * 64;
  const unsigned short* Pb = pnbf + (size_t)mat * D2P * 64;

  // A fragments: 64 o-rows x 64 k, held in 32 VGPRs/lane for the whole block
  bf16x8 a[4][2];
  #pragma unroll
  for (int t = 0; t < 4; t++)
    #pragma unroll
    for (int kc = 0; kc < 2; kc++)
      a[t][kc] = *(const bf16x8*)(Hb + (size_t)(o0 + t * 16 + m) * 64 + kc * 32 + q * 8);

  int dt0 = w * 12;
  int ntile = (w < 3) ? 12 : 10;      // 46 d-tiles total
  bool full = (o0 + 64 <= NOUT);      // last strip needs per-element o guard
  float local = 0.0f;

  for (int it = 0; it < ntile; it++) {
    int d0 = (dt0 + it) * 16;
    const unsigned short* bp = Pb + (size_t)(d0 + m) * 64 + q * 8;
    bf16x8 b0 = *(const bf16x8*)(bp);
    bf16x8 b1 = *(const bf16x8*)(bp + 32);
    floatx4 acc[4];
    #pragma unroll
    for (int t = 0; t < 4; t++) {
      acc[t] = (floatx4){0.f, 0.f, 0.f, 0.f};
      acc[t] = mfma16(a[t][0], b0, acc[t]);
      acc[t] = mfma16(a[t][1], b1, acc[t]);
    }
    int d = d0 + m;
    if (d < D2) {
      const float* Mrow = M + (size_t)d * NOUT;
      if (full) {
        #pragma unroll
        for (int t = 0; t < 4; t++) {
          int ob = o0 + t * 16 + q * 4;
          floatx2 m01 = *(const floatx2*)(Mrow + ob);       // 8B-aligned always
          floatx2 m23 = *(const floatx2*)(Mrow + ob + 2);
          float e0 = m01[0] - acc[t][0];
          float e1 = m01[1] - acc[t][1];
          float e2 = m23[0] - acc[t][2];
          float e3 = m23[1] - acc[t][3];
          local += e0 * e0 + e1 * e1 + e2 * e2 + e3 * e3;
        }
      } else {
        #pragma unroll
        for (int t = 0; t < 4; t++) {
          int ob = o0 + t * 16 + q * 4;
          #pragma unroll
          for (int reg = 0; reg < 4; reg++) {
            if (ob + reg < NOUT) {
              float e = Mrow[ob + reg] - acc[t][reg];
              local += e * e;
            }
          }
        }
      }
    }
  }
  for (int off = 32; off > 0; off >>= 1) local += __shfl_xor(local, off);
  __shared__ float shp[4];
  if (lane == 0) shp[w] = local;
  __syncthreads();
  if (threadIdx.x == 0) partial[blockIdx.x] = shp[0] + shp[1] + shp[2] + shp[3];
}

// ---------------- K5: final reductions ----------------
__global__ __launch_bounds__(256) void k_final(
    const float* __restrict__ sIJ, const float* __restrict__ sIK,
    const float* __restrict__ stIJ, const float* __restrict__ stIK,
    const float* __restrict__ l3partial, float* __restrict__ out) {
  int t = threadIdx.x;
  float l1 = 0.f, l2 = 0.f, ac = 0.f;
  for (int r = t; r < BATCH; r += 256) {
    float dij = sIJ[r] - sIK[r];
    l1 += softplusf(-dij);
    if (dij >= 0.0f) ac += 1.0f;
    float dst = stIJ[r] - stIK[r];
    l2 += softplusf(-dst);
  }
  double l3 = 0.0;
  for (int p = t; p < L3_BLOCKS; p += 256) l3 += (double)l3partial[p];
  __shared__ float sh1[4], sh2[4], sh3[4];
  __shared__ double sh4[4];
  for (int off = 32; off > 0; off >>= 1) {
    l1 += __shfl_xor(l1, off);
    l2 += __shfl_xor(l2, off);
    ac += __shfl_xor(ac, off);
    l3 += __shfl_xor(l3, off);
  }
  if ((t & 63) == 0) { sh1[t >> 6] = l1; sh2[t >> 6] = l2; sh3[t >> 6] = ac; sh4[t >> 6] = l3; }
  __syncthreads();
  if (t == 0) {
    double L1 = 0, L2 = 0, AC = 0, L3 = 0;
    for (int i = 0; i < 4; i++) { L1 += sh1[i]; L2 += sh2[i]; AC += sh3[i]; L3 += sh4[i]; }
    L1 /= BATCH; L2 /= BATCH; AC /= BATCH;
    L3 /= ((double)D2 * (double)NOUT);
    out[0] = (float)(L1 + L2 + 0.1 * L3);
    out[1] = (float)L1;
    out[2] = (float)L2;
    out[3] = (float)L3;
    out[4] = (float)AC;
  }
}

extern "C" void kernel_launch(void* const* d_in, const int* in_sizes, int n_in,
                              void* d_out, int out_size, void* d_ws, size_t ws_size,
                              hipStream_t stream) {
  (void)in_sizes; (void)n_in; (void)out_size; (void)ws_size;
  const float* i_f  = (const float*)d_in[0];
  const float* j_f  = (const float*)d_in[1];
  const float* k_f  = (const float*)d_in[2];
  const float* W_t  = (const float*)d_in[3];
  const float* b_t  = (const float*)d_in[4];
  const float* W_b  = (const float*)d_in[5];
  const float* b_b  = (const float*)d_in[6];
  const float* P_n  = (const float*)d_in[7];
  const float* N_n  = (const float*)d_in[8];
  const float* H1   = (const float*)d_in[9];
  const float* H2   = (const float*)d_in[10];
  const float* Mp   = (const float*)d_in[11];
  const float* Mn   = (const float*)d_in[12];
  float* out = (float*)d_out;
  char* ws = (char*)d_ws;

  const size_t OFF_FBF   = 0;
  const size_t OFF_WBFT  = OFF_FBF  + (size_t)3 * BATCH * KP * 2;   // 37,748,736
  const size_t OFF_PNBF  = OFF_WBFT + (size_t)2 * HID * KP * 2;
  const size_t OFF_PNBFT = OFF_PNBF + (size_t)2 * D2P * 64 * 2;
  const size_t OFF_HBFT  = OFF_PNBFT+ (size_t)2 * 64 * D2P * 2;
  const size_t OFF_SIJ   = OFF_HBFT + (size_t)2 * OUTP * 64 * 2;
  const size_t OFF_SIK   = OFF_SIJ  + (size_t)BATCH * 4;
  const size_t OFF_STIJ  = OFF_SIK  + (size_t)BATCH * 4;
  const size_t OFF_STIK  = OFF_STIJ + (size_t)BATCH * 4;
  const size_t OFF_SS    = OFF_STIK + (size_t)BATCH * 4;
  const size_t OFF_CN    = OFF_SS   + 512;
  const size_t OFF_L3P   = OFF_CN   + 512;   // L3_BLOCKS floats

  unsigned short* fbf   = (unsigned short*)(ws + OFF_FBF);
  unsigned short* wbfT  = (unsigned short*)(ws + OFF_WBFT);
  unsigned short* pnbf  = (unsigned short*)(ws + OFF_PNBF);
  unsigned short* pnbfT = (unsigned short*)(ws + OFF_PNBFT);
  unsigned short* hbfT  = (unsigned short*)(ws + OFF_HBFT);
  float*  sIJ  = (float*)(ws + OFF_SIJ);
  float*  sIK  = (float*)(ws + OFF_SIK);
  float*  stIJ = (float*)(ws + OFF_STIJ);
  float*  stIK = (float*)(ws + OFF_STIK);
  float*  ss   = (float*)(ws + OFF_SS);
  float*  cn   = (float*)(ws + OFF_CN);
  float*  l3p  = (float*)(ws + OFF_L3P);

  // zero: sIJ + sIK (atomically accumulated by k_emb)
  hipMemsetAsync(ws + OFF_SIJ, 0, (size_t)BATCH * 4 * 2, stream);

  k_conv_feat<<<(3 * BATCH * 48 + 255) / 256, 256, 0, stream>>>(i_f, j_f, k_f, fbf);
  k_conv_w   <<<dim3(HID, 2),  128, 0, stream>>>(W_t, W_b, wbfT);
  k_conv_pn  <<<dim3(D2P, 2),   64, 0, stream>>>(P_n, N_n, pnbf, pnbfT);
  k_conv_h   <<<dim3(195, 2),  256, 0, stream>>>(H1, H2, hbfT);

  k_style_scalar<<<120, 256, 0, stream>>>(P_n, N_n, W_t, b_t, W_b, b_b, ss, cn);
  k_emb         <<<dim3(BATCH / 64, 2), 256, 0, stream>>>(fbf, wbfT, b_t, b_b, sIJ, sIK);
  k_style_assign<<<BATCH / 32, 256, 0, stream>>>(fbf, pnbfT, cn, ss, stIJ, stIK);
  k_loss3       <<<L3_BLOCKS, 256, 0, stream>>>(pnbf, hbfT, Mp, Mn, l3p);
  k_final       <<<1, 256, 0, stream>>>(sIJ, sIK, stIJ, stIK, l3p, out);
}

// Round 4
// 641.863 us; speedup vs baseline: 2.2847x; 1.0506x over previous
//
#include <hip/hip_runtime.h>
#include <math.h>

#define BATCH 16384
#define IND   362
#define KP    384      // per-feature K padded to 384 (12 x 32)
#define HID   256
#define STY   60
#define NOUT  49710
#define OUTP  49792    // padded o-stride for hbfT
#define D2    724
#define D2P   768
#define NSTRIP 777     // ceil(NOUT/64)
#define L3_BLOCKS (2 * NSTRIP)

// ---- k_prep block ranges (256 threads each) ----
#define NB_SS   120                       // style_scalar
#define NB_CH   390                       // conv_h: 2 x 195
#define NB_CW   768                       // conv_w: 2*256*384/256
#define NB_CPN  384                       // conv_pn: 2*768*64/256
#define NB_CF   9216                      // conv_feat: 3*16384*48/256
#define NB_PREP (NB_SS + NB_CH + NB_CW + NB_CPN + NB_CF)

// ---- k_main block ranges ----
#define NB_EMB  512
#define NB_SA   512
#define NB_MAIN (L3_BLOCKS + NB_EMB + NB_SA)

typedef __bf16 bf16x8 __attribute__((ext_vector_type(8)));
typedef float  floatx4 __attribute__((ext_vector_type(4)));
typedef float  floatx2 __attribute__((ext_vector_type(2)));

__device__ inline floatx4 mfma16(bf16x8 a, bf16x8 b, floatx4 c) {
  return __builtin_amdgcn_mfma_f32_16x16x32_bf16(a, b, c, 0, 0, 0);
}

__device__ inline unsigned short f32_to_bf16(float x) {
  unsigned int u = __float_as_uint(x);
  unsigned int r = (u + 0x7FFFu + ((u >> 16) & 1u)) >> 16;
  return (unsigned short)r;
}

__device__ inline float sigm_fast(float x) { return 1.0f / (1.0f + __expf(-x)); }
__device__ inline float softplusf(float z) { return fmaxf(z, 0.0f) + log1pf(expf(-fabsf(z))); }

// =================== PHASE A: prep (converts + style scalars) ===================
__global__ __launch_bounds__(256) void k_prep(
    const float* __restrict__ fi, const float* __restrict__ fj, const float* __restrict__ fk,
    const float* __restrict__ Wt, const float* __restrict__ btop,
    const float* __restrict__ Wb, const float* __restrict__ bbot,
    const float* __restrict__ Pn, const float* __restrict__ Nn,
    const float* __restrict__ H1, const float* __restrict__ H2,
    unsigned short* __restrict__ fbf, unsigned short* __restrict__ wbfT,
    unsigned short* __restrict__ pnbf, unsigned short* __restrict__ pnbfT,
    unsigned short* __restrict__ hbfT,
    float* __restrict__ ss, float* __restrict__ cn) {
  __shared__ float sel[D2];
  __shared__ float shr[4];
  int b = blockIdx.x;
  int t = threadIdx.x;

  if (b < NB_SS) {
    // ---- per-style scalar scores + column norms (fp32 exact) ----
    int s  = b % STY;
    int mt = b / STY;
    const float* M = mt ? Nn : Pn;
    float cnp = 0.0f;
    for (int d = t; d < D2; d += 256) {
      float v = fmaxf(M[(size_t)d * STY + s], 0.0f);
      sel[d] = v;
      cnp += v * v;
    }
    __syncthreads();
    float at = btop[t], ab = bbot[t];
    for (int d = 0; d < IND; d++) at = fmaf(sel[d],       Wt[(size_t)d * HID + t], at);
    for (int d = 0; d < IND; d++) ab = fmaf(sel[IND + d], Wb[(size_t)d * HID + t], ab);
    float prod = (1.0f / (1.0f + expf(-at))) * (1.0f / (1.0f + expf(-ab)));
    for (int off = 32; off > 0; off >>= 1) prod += __shfl_xor(prod, off);
    if ((t & 63) == 0) shr[t >> 6] = prod;
    __syncthreads();
    if (t == 0) ss[mt * 64 + s] = shr[0] + shr[1] + shr[2] + shr[3];
    __syncthreads();
    for (int off = 32; off > 0; off >>= 1) cnp += __shfl_xor(cnp, off);
    if ((t & 63) == 0) shr[t >> 6] = cnp;
    __syncthreads();
    if (t == 0) cn[mt * 64 + s] = shr[0] + shr[1] + shr[2] + shr[3];
    return;
  }
  b -= NB_SS;

  if (b < NB_CH) {
    // ---- H1/H2 relu -> hbfT [2][49792][64] bf16 ----
    int o = (b % 195) * 256 + t;
    int m = b / 195;
    if (o >= OUTP) return;
    const float* H = m ? H2 : H1;
    unsigned short* dst = hbfT + ((size_t)m * OUTP + o) * 64;
    bool ov = (o < NOUT);
    #pragma unroll
    for (int g = 0; g < 8; g++) {
      unsigned int wv[4];
      #pragma unroll
      for (int e = 0; e < 4; e++) {
        int kk = g * 8 + e * 2;
        float lo = (ov && kk < STY)     ? fmaxf(H[(size_t)kk * NOUT + o], 0.0f) : 0.0f;
        float hi = (ov && kk + 1 < STY) ? fmaxf(H[(size_t)(kk + 1) * NOUT + o], 0.0f) : 0.0f;
        wv[e] = (unsigned)f32_to_bf16(lo) | ((unsigned)f32_to_bf16(hi) << 16);
      }
      uint4 v; v.x = wv[0]; v.y = wv[1]; v.z = wv[2]; v.w = wv[3];
      *(uint4*)(dst + g * 8) = v;
    }
    return;
  }
  b -= NB_CH;

  if (b < NB_CW) {
    // ---- W -> wbfT [2][256][384] (flat) ----
    int idx = b * 256 + t;
    int k = idx % KP;
    int rem = idx / KP;
    int h = rem % HID;
    int mm = rem / HID;
    const float* W = mm ? Wb : Wt;
    wbfT[idx] = f32_to_bf16(k < IND ? W[(size_t)k * HID + h] : 0.0f);
    return;
  }
  b -= NB_CW;

  if (b < NB_CPN) {
    // ---- P/N relu -> pnbf [2][768][64] + pnbfT [2][64][768] ----
    int u = b * 256 + t;
    int s = u & 63;
    int v = u >> 6;           // 0..1535
    int m = (v >= D2P) ? 1 : 0;
    int d = v - m * D2P;
    const float* M = m ? Nn : Pn;
    float x = (d < D2 && s < STY) ? fmaxf(M[(size_t)d * STY + s], 0.0f) : 0.0f;
    unsigned short bb = f32_to_bf16(x);
    pnbf[((size_t)m * D2P + d) * 64 + s] = bb;
    int k = (d < IND) ? d : (d < D2 ? d + 22 : (d < 746 ? d - IND : d));
    pnbfT[((size_t)m * 64 + s) * D2P + k] = bb;
    return;
  }
  b -= NB_CPN;

  {
    // ---- features -> fbf bf16 (uint4 stores) ----
    long u = (long)b * 256 + t;
    int g = (int)(u % 48);
    long rf = u / 48;
    int row = (int)(rf % BATCH);
    int f = (int)(rf / BATCH);
    const float* src = (f == 0) ? fi : (f == 1 ? fj : fk);
    int d0 = g * 8;
    const float* sp = src + (size_t)row * IND + d0;
    unsigned int wv[4];
    #pragma unroll
    for (int e = 0; e < 4; e++) {
      int dd = d0 + 2 * e;
      float lo = (dd < IND)     ? sp[2 * e]     : 0.0f;
      float hi = (dd + 1 < IND) ? sp[2 * e + 1] : 0.0f;
      wv[e] = (unsigned)f32_to_bf16(lo) | ((unsigned)f32_to_bf16(hi) << 16);
    }
    uint4 v; v.x = wv[0]; v.y = wv[1]; v.z = wv[2]; v.w = wv[3];
    *(uint4*)(fbf + ((size_t)f * BATCH + row) * KP + d0) = v;
  }
}

// =================== PHASE B: main (loss3 + emb + style_assign fused) ===================
__global__ __launch_bounds__(256) void k_main(
    const unsigned short* __restrict__ fbf, const unsigned short* __restrict__ wbfT,
    const unsigned short* __restrict__ pnbf, const unsigned short* __restrict__ pnbfT,
    const unsigned short* __restrict__ hbfT,
    const float* __restrict__ btop, const float* __restrict__ bbot,
    const float* __restrict__ cn, const float* __restrict__ ss,
    const float* __restrict__ mp, const float* __restrict__ mn,
    float* __restrict__ sIJ, float* __restrict__ sIK,
    float* __restrict__ stIJ, float* __restrict__ stIK,
    float* __restrict__ partial) {
  __shared__ float shp[4];
  int w = threadIdx.x >> 6, lane = threadIdx.x & 63;
  int m = lane & 15, q = lane >> 4;
  int b = blockIdx.x;

  if (b < L3_BLOCKS) {
    // ---------- loss3: one block per (mat, 64-o strip); hbfT strip in regs; prefetched M ----------
    int strip = b % NSTRIP;
    int mat   = b / NSTRIP;
    int o0 = strip * 64;
    const float* M = mat ? mn : mp;
    const unsigned short* Hb = hbfT + (size_t)mat * OUTP * 64;
    const unsigned short* Pb = pnbf + (size_t)mat * D2P * 64;

    bf16x8 a[4][2];
    #pragma unroll
    for (int t = 0; t < 4; t++)
      #pragma unroll
      for (int kc = 0; kc < 2; kc++)
        a[t][kc] = *(const bf16x8*)(Hb + (size_t)(o0 + t * 16 + m) * 64 + kc * 32 + q * 8);

    bool full = (o0 + 64 <= NOUT);
    float local = 0.0f;
    floatx2 pcur[8], pnxt[8];
    #pragma unroll
    for (int i = 0; i < 8; i++) { pcur[i] = (floatx2){0.f, 0.f}; pnxt[i] = (floatx2){0.f, 0.f}; }

    auto LOAD = [&](int dt, floatx2* dst) {
      int d = dt * 16 + m;
      if (d < D2) {
        const float* Mrow = M + (size_t)d * NOUT + o0;
        if (full) {
          #pragma unroll
          for (int t = 0; t < 4; t++) {
            int ob = t * 16 + q * 4;
            dst[2 * t]     = *(const floatx2*)(Mrow + ob);
            dst[2 * t + 1] = *(const floatx2*)(Mrow + ob + 2);
          }
        } else {
          #pragma unroll
          for (int t = 0; t < 4; t++) {
            int ob = t * 16 + q * 4;
            floatx2 v0 = {0.f, 0.f}, v1 = {0.f, 0.f};
            if (o0 + ob     < NOUT) v0[0] = Mrow[ob];
            if (o0 + ob + 1 < NOUT) v0[1] = Mrow[ob + 1];
            if (o0 + ob + 2 < NOUT) v1[0] = Mrow[ob + 2];
            if (o0 + ob + 3 < NOUT) v1[1] = Mrow[ob + 3];
            dst[2 * t] = v0; dst[2 * t + 1] = v1;
          }
        }
      }
    };

    LOAD(w, pcur);                          // preload first tile
    for (int dt = w; dt < 46; dt += 4) {    // waves interleave d-tiles stride 4
      if (dt + 4 < 46) LOAD(dt + 4, pnxt);  // prefetch next (load-use distance = 1 iter)
      int d0 = dt * 16;
      const unsigned short* bp = Pb + (size_t)(d0 + m) * 64 + q * 8;
      bf16x8 b0 = *(const bf16x8*)(bp);
      bf16x8 b1 = *(const bf16x8*)(bp + 32);
      floatx4 acc[4];
      #pragma unroll
      for (int t = 0; t < 4; t++) {
        acc[t] = (floatx4){0.f, 0.f, 0.f, 0.f};
        acc[t] = mfma16(a[t][0], b0, acc[t]);
        acc[t] = mfma16(a[t][1], b1, acc[t]);
      }
      if (d0 + m < D2) {
        #pragma unroll
        for (int t = 0; t < 4; t++) {
          float e0 = pcur[2 * t][0]     - acc[t][0];
          float e1 = pcur[2 * t][1]     - acc[t][1];
          float e2 = pcur[2 * t + 1][0] - acc[t][2];
          float e3 = pcur[2 * t + 1][1] - acc[t][3];
          local += e0 * e0 + e1 * e1 + e2 * e2 + e3 * e3;
        }
      }
      #pragma unroll
      for (int i = 0; i < 8; i++) pcur[i] = pnxt[i];
    }
    for (int off = 32; off > 0; off >>= 1) local += __shfl_xor(local, off);
    if (lane == 0) shp[w] = local;
    __syncthreads();
    if (threadIdx.x == 0) partial[b] = shp[0] + shp[1] + shp[2] + shp[3];
    return;
  }
  b -= L3_BLOCKS;

  if (b < NB_EMB) {
    // ---------- embedding GEMMs + ij/ik scores ----------
    int r0 = (b & 255) * 64 + w * 16;
    int hb = (b >> 8) * 128;
    const unsigned short* fi = fbf + (size_t)(r0 + m) * KP + q * 8;
    const unsigned short* fj = fi + (size_t)BATCH * KP;
    const unsigned short* fk = fj + (size_t)BATCH * KP;
    floatx4 accI[8], accJ[8], accK[8];
    #pragma unroll
    for (int nt = 0; nt < 8; nt++) {
      accI[nt] = (floatx4){0.f, 0.f, 0.f, 0.f};
      accJ[nt] = (floatx4){0.f, 0.f, 0.f, 0.f};
      accK[nt] = (floatx4){0.f, 0.f, 0.f, 0.f};
    }
    for (int kc = 0; kc < 12; kc++) {
      bf16x8 ai = *(const bf16x8*)(fi + kc * 32);
      bf16x8 aj = *(const bf16x8*)(fj + kc * 32);
      bf16x8 ak = *(const bf16x8*)(fk + kc * 32);
      #pragma unroll
      for (int nt = 0; nt < 8; nt++) {
        int n = hb + nt * 16 + m;
        const unsigned short* wp = wbfT + (size_t)n * KP + kc * 32 + q * 8;
        bf16x8 bt8 = *(const bf16x8*)(wp);
        bf16x8 bb8 = *(const bf16x8*)(wp + (size_t)HID * KP);
        accI[nt] = mfma16(ai, bt8, accI[nt]);
        accJ[nt] = mfma16(aj, bb8, accJ[nt]);
        accK[nt] = mfma16(ak, bb8, accK[nt]);
      }
    }
    float sij[4] = {0.f, 0.f, 0.f, 0.f}, sik[4] = {0.f, 0.f, 0.f, 0.f};
    #pragma unroll
    for (int nt = 0; nt < 8; nt++) {
      int n = hb + nt * 16 + m;
      float vbt = btop[n], vbb = bbot[n];
      #pragma unroll
      for (int reg = 0; reg < 4; reg++) {
        float ti = sigm_fast(accI[nt][reg] + vbt);
        float tj = sigm_fast(accJ[nt][reg] + vbb);
        float tk = sigm_fast(accK[nt][reg] + vbb);
        sij[reg] += ti * tj;
        sik[reg] += ti * tk;
      }
    }
    #pragma unroll
    for (int reg = 0; reg < 4; reg++) {
      for (int off = 1; off < 16; off <<= 1) {
        sij[reg] += __shfl_xor(sij[reg], off);
        sik[reg] += __shfl_xor(sik[reg], off);
      }
    }
    if (m == 0) {
      #pragma unroll
      for (int reg = 0; reg < 4; reg++) {
        int row = r0 + q * 4 + reg;
        atomicAdd(&sIJ[row], sij[reg]);
        atomicAdd(&sIK[row], sik[reg]);
      }
    }
    return;
  }
  b -= NB_EMB;

  {
    // ---------- style argmin + gather ----------
    int mat = w & 1;
    int r0 = b * 32 + (w >> 1) * 16;
    const unsigned short* fA = fbf + (size_t)(r0 + m) * KP + q * 8;
    const unsigned short* fB = fA + (size_t)(1 + mat) * BATCH * KP;
    const unsigned short* Bp = pnbfT + (size_t)mat * 64 * D2P + q * 8;
    floatx4 acc[4];
    #pragma unroll
    for (int nt = 0; nt < 4; nt++) acc[nt] = (floatx4){0.f, 0.f, 0.f, 0.f};
    for (int kc = 0; kc < 24; kc++) {
      bf16x8 a = (kc < 12) ? *(const bf16x8*)(fA + kc * 32)
                           : *(const bf16x8*)(fB + (kc - 12) * 32);
      #pragma unroll
      for (int nt = 0; nt < 4; nt++) {
        bf16x8 bb = *(const bf16x8*)(Bp + (size_t)(nt * 16 + m) * D2P + kc * 32);
        acc[nt] = mfma16(a, bb, acc[nt]);
      }
    }
    const float* cnm = cn + mat * 64;
    float bv[4]; int bi[4];
    #pragma unroll
    for (int reg = 0; reg < 4; reg++) { bv[reg] = __builtin_inff(); bi[reg] = 1 << 30; }
    #pragma unroll
    for (int nt = 0; nt < 4; nt++) {
      int s = nt * 16 + m;
      float c = cnm[s & 63];
      #pragma unroll
      for (int reg = 0; reg < 4; reg++) {
        float d2 = (s < STY) ? (c - 2.0f * acc[nt][reg]) : __builtin_inff();
        if (d2 < bv[reg] || (d2 == bv[reg] && s < bi[reg])) { bv[reg] = d2; bi[reg] = s; }
      }
    }
    for (int off = 1; off < 16; off <<= 1) {
      #pragma unroll
      for (int reg = 0; reg < 4; reg++) {
        float ov = __shfl_xor(bv[reg], off);
        int   oi = __shfl_xor(bi[reg], off);
        if (ov < bv[reg] || (ov == bv[reg] && oi < bi[reg])) { bv[reg] = ov; bi[reg] = oi; }
      }
    }
    if (m == 0) {
      float* dst = mat ? stIK : stIJ;
      const float* ssm = ss + mat * 64;
      #pragma unroll
      for (int reg = 0; reg < 4; reg++) dst[r0 + q * 4 + reg] = ssm[bi[reg]];
    }
  }
}

// =================== PHASE C: final reductions ===================
__global__ __launch_bounds__(256) void k_final(
    const float* __restrict__ sIJ, const float* __restrict__ sIK,
    const float* __restrict__ stIJ, const float* __restrict__ stIK,
    const float* __restrict__ l3partial, float* __restrict__ out) {
  int t = threadIdx.x;
  float l1 = 0.f, l2 = 0.f, ac = 0.f;
  for (int r = t; r < BATCH; r += 256) {
    float dij = sIJ[r] - sIK[r];
    l1 += softplusf(-dij);
    if (dij >= 0.0f) ac += 1.0f;
    float dst = stIJ[r] - stIK[r];
    l2 += softplusf(-dst);
  }
  double l3 = 0.0;
  for (int p = t; p < L3_BLOCKS; p += 256) l3 += (double)l3partial[p];
  __shared__ float sh1[4], sh2[4], sh3[4];
  __shared__ double sh4[4];
  for (int off = 32; off > 0; off >>= 1) {
    l1 += __shfl_xor(l1, off);
    l2 += __shfl_xor(l2, off);
    ac += __shfl_xor(ac, off);
    l3 += __shfl_xor(l3, off);
  }
  if ((t & 63) == 0) { sh1[t >> 6] = l1; sh2[t >> 6] = l2; sh3[t >> 6] = ac; sh4[t >> 6] = l3; }
  __syncthreads();
  if (t == 0) {
    double L1 = 0, L2 = 0, AC = 0, L3 = 0;
    for (int i = 0; i < 4; i++) { L1 += sh1[i]; L2 += sh2[i]; AC += sh3[i]; L3 += sh4[i]; }
    L1 /= BATCH; L2 /= BATCH; AC /= BATCH;
    L3 /= ((double)D2 * (double)NOUT);
    out[0] = (float)(L1 + L2 + 0.1 * L3);
    out[1] = (float)L1;
    out[2] = (float)L2;
    out[3] = (float)L3;
    out[4] = (float)AC;
  }
}

extern "C" void kernel_launch(void* const* d_in, const int* in_sizes, int n_in,
                              void* d_out, int out_size, void* d_ws, size_t ws_size,
                              hipStream_t stream) {
  (void)in_sizes; (void)n_in; (void)out_size; (void)ws_size;
  const float* i_f  = (const float*)d_in[0];
  const float* j_f  = (const float*)d_in[1];
  const float* k_f  = (const float*)d_in[2];
  const float* W_t  = (const float*)d_in[3];
  const float* b_t  = (const float*)d_in[4];
  const float* W_b  = (const float*)d_in[5];
  const float* b_b  = (const float*)d_in[6];
  const float* P_n  = (const float*)d_in[7];
  const float* N_n  = (const float*)d_in[8];
  const float* H1   = (const float*)d_in[9];
  const float* H2   = (const float*)d_in[10];
  const float* Mp   = (const float*)d_in[11];
  const float* Mn   = (const float*)d_in[12];
  float* out = (float*)d_out;
  char* ws = (char*)d_ws;

  const size_t OFF_FBF   = 0;
  const size_t OFF_WBFT  = OFF_FBF  + (size_t)3 * BATCH * KP * 2;
  const size_t OFF_PNBF  = OFF_WBFT + (size_t)2 * HID * KP * 2;
  const size_t OFF_PNBFT = OFF_PNBF + (size_t)2 * D2P * 64 * 2;
  const size_t OFF_HBFT  = OFF_PNBFT+ (size_t)2 * 64 * D2P * 2;
  const size_t OFF_SIJ   = OFF_HBFT + (size_t)2 * OUTP * 64 * 2;
  const size_t OFF_SIK   = OFF_SIJ  + (size_t)BATCH * 4;
  const size_t OFF_STIJ  = OFF_SIK  + (size_t)BATCH * 4;
  const size_t OFF_STIK  = OFF_STIJ + (size_t)BATCH * 4;
  const size_t OFF_SS    = OFF_STIK + (size_t)BATCH * 4;
  const size_t OFF_CN    = OFF_SS   + 512;
  const size_t OFF_L3P   = OFF_CN   + 512;

  unsigned short* fbf   = (unsigned short*)(ws + OFF_FBF);
  unsigned short* wbfT  = (unsigned short*)(ws + OFF_WBFT);
  unsigned short* pnbf  = (unsigned short*)(ws + OFF_PNBF);
  unsigned short* pnbfT = (unsigned short*)(ws + OFF_PNBFT);
  unsigned short* hbfT  = (unsigned short*)(ws + OFF_HBFT);
  float*  sIJ  = (float*)(ws + OFF_SIJ);
  float*  sIK  = (float*)(ws + OFF_SIK);
  float*  stIJ = (float*)(ws + OFF_STIJ);
  float*  stIK = (float*)(ws + OFF_STIK);
  float*  ss   = (float*)(ws + OFF_SS);
  float*  cn   = (float*)(ws + OFF_CN);
  float*  l3p  = (float*)(ws + OFF_L3P);

  hipMemsetAsync(ws + OFF_SIJ, 0, (size_t)BATCH * 4 * 2, stream);

  k_prep<<<NB_PREP, 256, 0, stream>>>(i_f, j_f, k_f, W_t, b_t, W_b, b_b,
                                      P_n, N_n, H1, H2,
                                      fbf, wbfT, pnbf, pnbfT, hbfT, ss, cn);
  k_main<<<NB_MAIN, 256, 0, stream>>>(fbf, wbfT, pnbf, pnbfT, hbfT,
                                      b_t, b_b, cn, ss, Mp, Mn,
                                      sIJ, sIK, stIJ, stIK, l3p);
  k_final<<<1, 256, 0, stream>>>(sIJ, sIK, stIJ, stIK, l3p, out);
}